// Round 26
// baseline (44.534 us; speedup 1.0000x reference)
//
#include <hip/hip_runtime.h>
#include <hip/hip_fp16.h>

typedef _Float16 half8v __attribute__((ext_vector_type(8)));
typedef __fp16  pk16x2 __attribute__((ext_vector_type(2)));
typedef float f32x4 __attribute__((ext_vector_type(4)));

#define DEV __device__ __forceinline__
DEV float crelu(float x) { return fminf(fmaxf(x, -1.0f), 1.0f); }

DEV unsigned int pkrtz_u32(float a, float b) {
    pk16x2 p = __builtin_amdgcn_cvt_pkrtz(a, b);
    return __builtin_bit_cast(unsigned int, p);
}

DEV void lgkm0() { asm volatile("s_waitcnt lgkmcnt(0)" ::: "memory"); }
DEV void cfence() { asm volatile("" ::: "memory"); }

// ---------------------------------------------------------------------------
// ws layout (identical to r19-r24):
//   floats [0, 1152): w3t [16][2] @ 1120 (L3)
//   float 6000: e1bias48 | float 6048: e2bias48 | float 6096: e3p48
//   byte 19200: f16 frags: W1 [3][64][8] (A-side), W2 [64][8] (A-side)
//   byte 32768: e1bf [3 ks][3 nt][64][8] f16  E1^T, K=96
//   byte 45056: e2bf [2 ks][3 nt][64][8] f16  E2^T, K=64
// ---------------------------------------------------------------------------
__global__ void prep_kernel(const float* __restrict__ W1, const float* __restrict__ W2,
                            const float* __restrict__ W3, const float* __restrict__ E1,
                            const float* __restrict__ E2, const float* __restrict__ e1b,
                            const float* __restrict__ e2b, const float* __restrict__ E3,
                            float* __restrict__ ws) {
    int t = threadIdx.x + blockIdx.x * blockDim.x;
    if (t < 864) {
        int s = t >> 4, o = t & 15;
        ws[t] = W1[o * 54 + s];
    } else if (t < 864 + 256) {
        int u = t - 864; int i = u >> 4, o = u & 15;
        ws[t] = W2[o * 16 + i];
    } else if (t < 1120 + 32) {
        int u = t - 1120; int i = u >> 1, o = u & 1;
        ws[t] = W3[o * 16 + i];
    } else if (t >= 8192 && t < 8192 + 1536) {
        _Float16* fr = (_Float16*)((char*)ws + 19200);
        int u = t - 8192;
        int ks = u >> 9, l = (u >> 3) & 63, j = u & 7;
        int n = l & 15;
        int kg = ks * 32 + ((l >> 4) << 3) + j;
        int ox = kg / 24, rem = kg - ox * 24, cy = rem >> 3, f = rem & 7;
        float v = (kg < 72 && f < 6) ? W1[n * 54 + ox * 18 + cy * 6 + f] : 0.0f;
        fr[u] = (_Float16)v;
    } else if (t >= 10240 && t < 10240 + 512) {
        _Float16* fr = (_Float16*)((char*)ws + 19200) + 1536;
        int u = t - 10240;
        int l = u >> 3, j = u & 7;
        int n = l & 15;
        int k = ((l >> 4) << 3) + j;
        float v = (k < 16) ? W2[n * 16 + k] : 0.0f;
        fr[u] = (_Float16)v;
    } else if (t >= 12288 && t < 12288 + 4608) {
        _Float16* fr = (_Float16*)((char*)ws + 32768);
        int u = t - 12288;
        int ks = u / 1536, rem = u % 1536;
        int nt = rem / 512;
        int l = (rem >> 3) & 63, j = u & 7;
        int k = ks * 32 + ((l >> 4) << 3) + j;
        int o = nt * 16 + (l & 15);
        float v = (k < 73 && o < 34) ? E1[o * 73 + k] : 0.0f;
        fr[u] = (_Float16)v;
    } else if (t >= 18432 && t < 18432 + 3072) {
        _Float16* fr = (_Float16*)((char*)ws + 45056);
        int u = t - 18432;
        int ks = u / 1536, rem = u % 1536;
        int nt = rem / 512;
        int l = (rem >> 3) & 63, j = u & 7;
        int k = ks * 32 + ((l >> 4) << 3) + j;
        int o = nt * 16 + (l & 15);
        float v = (k < 34 && o < 34) ? E2[o * 34 + k] : 0.0f;
        fr[u] = (_Float16)v;
    } else if (t >= 22528 && t < 22528 + 48) {
        int u = t - 22528; ws[6000 + u] = (u < 34) ? e1b[u] : 0.0f;
    } else if (t >= 22592 && t < 22592 + 48) {
        int u = t - 22592; ws[6048 + u] = (u < 34) ? e2b[u] : 0.0f;
    } else if (t >= 22656 && t < 22656 + 48) {
        int u = t - 22656; ws[6096 + u] = (u < 34) ? E3[u] : 0.0f;
    }
}

// ---------------------------------------------------------------------------
// FUSED (r24 base) with the conv loop split into TWO PASSES for ILP:
//   pass 1: all 9 tiles' {3 ds_read -> 3 L1 MFMA -> crelu-pack} -> d0a/d1a[9]
//   pass 2: all 9 tiles' {4 shfl gather -> L2 MFMA -> L3 dot -> 4 shfl_xor
//           -> vloc write}
// Each pass is 9 independent chains -> deep pipelining (r24's single chain
// was ~1.5 tiles in flight at VGPR=52). Registers d0a/d1a statically indexed.
// Everything else byte-identical to r24.
// ---------------------------------------------------------------------------
__global__ __launch_bounds__(256, 2) void lila_kernel(
    const float* __restrict__ inp,
    const float* __restrict__ b1, const float* __restrict__ b2,
    const float* __restrict__ b3, const float* __restrict__ e3v,
    const float* __restrict__ ws, const _Float16* __restrict__ frag,
    float* __restrict__ out)
{
    __shared__ half8v grids[4 * 288];        // 18432 B
    __shared__ unsigned int vloc[576];       // [4 waves][144] = 2304 B
    __shared__ _Float16 hset[17 * 48];       // 1632 B (head, wave 0)
    const int tid  = threadIdx.x;
    const int wid  = tid >> 6;
    const int lane = tid & 63;
    const int baseE = blockIdx.x * 16;
    const int baseP = baseE + wid * 4;

    half8v* grid = grids + wid * 288;

    const int r = lane & 15;
    const int g = lane >> 4;

    // ---- zero the wave's grid region (288 half8s; pad cells must be 0) ----
    {
        const uint4 z = {0u, 0u, 0u, 0u};
        #pragma unroll
        for (int i = 0; i < 5; ++i) {
            const int idx = lane + i * 64;
            if (i < 4 || idx < 288)
                *reinterpret_cast<uint4*>(grid + idx) = z;
        }
    }
    cfence();

    // ---- stage 4 elements' grids ----
    {
        const int es = lane >> 4, m = lane & 15;
        const float* __restrict__ src = inp + (size_t)(baseP + es) * 385 + 24 * m;
        #pragma unroll
        for (int c = 0; c < 4; ++c) {
            float f0 = src[c * 6 + 0], f1 = src[c * 6 + 1], f2 = src[c * 6 + 2];
            float f3 = src[c * 6 + 3], f4 = src[c * 6 + 4], f5 = src[c * 6 + 5];
            uint4 q;
            q.x = pkrtz_u32(f0, f1);
            q.y = pkrtz_u32(f2, f3);
            q.z = pkrtz_u32(f4, f5);
            q.w = q.z;                        // finite pad (zero-weighted)
            *reinterpret_cast<uint4*>(grid + es * 72 + 4 * m + c) = q;
        }
    }
    cfence();

    {   // ---- conv: two-pass, register-resident ----
        const half8v* __restrict__ fr8 = (const half8v*)frag;
        half8v W1f0 = fr8[0 * 64 + lane];
        half8v W1f1 = fr8[1 * 64 + lane];
        half8v W1f2 = fr8[2 * 64 + lane];
        half8v W2fA = fr8[3 * 64 + lane];

        int off[3];
        #pragma unroll
        for (int ks = 0; ks < 3; ++ks) {
            int c = ks * 4 + g;
            int ox = c / 3, cy = c - 3 * ox;
            off[ks] = ox * 8 + cy;
        }

        float b1q[4], b2q[4], w3a[4], w3b[4];
        const float* __restrict__ w3t = ws + 1120;
        #pragma unroll
        for (int q = 0; q < 4; ++q) {
            b1q[q] = b1[g * 4 + q];
            b2q[q] = b2[g * 4 + q];
            w3a[q] = w3t[(g * 4 + q) * 2 + 0];
            w3b[q] = w3t[(g * 4 + q) * 2 + 1];
        }
        const float b30 = b3[0], b31 = b3[1];

        const int s0 = r + (((g << 1) + 0) & 3) * 16;
        const int s1 = r + (((g << 1) + 1) & 3) * 16;

        // ---- pass 1: layer 1 for all 9 tiles -> packed d0a/d1a ----
        unsigned int d0a[9], d1a[9];
        {
            int w = r, ebase = 0;
            #pragma unroll
            for (int t = 0; t < 9; ++t) {
                const int x = (w * 43) >> 8;
                const int y = w - x * 6;
                const int cellb = ebase + x * 8 + y;

                half8v a0 = grid[cellb + off[0]];
                half8v a1 = grid[cellb + off[1]];
                half8v a2 = grid[cellb + off[2]];

                f32x4 acc = {b1q[0], b1q[1], b1q[2], b1q[3]};
                acc = __builtin_amdgcn_mfma_f32_16x16x32_f16(W1f0, a0, acc, 0, 0, 0);
                acc = __builtin_amdgcn_mfma_f32_16x16x32_f16(W1f1, a1, acc, 0, 0, 0);
                acc = __builtin_amdgcn_mfma_f32_16x16x32_f16(W1f2, a2, acc, 0, 0, 0);

                d0a[t] = pkrtz_u32(crelu(acc[0]), crelu(acc[1]));
                d1a[t] = pkrtz_u32(crelu(acc[2]), crelu(acc[3]));

                w += 16;
                if (w >= 36) { w -= 36; ebase += 72; }
            }
        }

        // ---- pass 2: shfl gather + layer 2 + layer 3 for all 9 tiles ----
        {
            int w = r, ebase = 0;
            #pragma unroll
            for (int t = 0; t < 9; ++t) {
                uint4 bw;
                bw.x = (unsigned int)__shfl((int)d0a[t], s0);
                bw.y = (unsigned int)__shfl((int)d1a[t], s0);
                bw.z = (unsigned int)__shfl((int)d0a[t], s1);
                bw.w = (unsigned int)__shfl((int)d1a[t], s1);
                if (g >= 2) { bw.x = 0u; bw.y = 0u; bw.z = 0u; bw.w = 0u; }
                const half8v B2in = __builtin_bit_cast(half8v, bw);

                f32x4 c2 = {b2q[0], b2q[1], b2q[2], b2q[3]};
                c2 = __builtin_amdgcn_mfma_f32_16x16x32_f16(W2fA, B2in, c2, 0, 0, 0);

                float v0p = 0.0f, v1p = 0.0f;
                #pragma unroll
                for (int q = 0; q < 4; ++q) {
                    const float hv = crelu(c2[q]);
                    v0p = fmaf(hv, w3a[q], v0p);
                    v1p = fmaf(hv, w3b[q], v1p);
                }
                v0p += __shfl_xor(v0p, 16);
                v0p += __shfl_xor(v0p, 32);
                v1p += __shfl_xor(v1p, 16);
                v1p += __shfl_xor(v1p, 32);
                if (g == 0)
                    vloc[wid * 144 + (ebase >> 1) + w] =
                        pkrtz_u32(crelu(v0p + b30), crelu(v1p + b31));

                w += 16;
                if (w >= 36) { w -= 36; ebase += 72; }
            }
        }
    }

    __syncthreads();                          // vloc complete
    if (wid != 0) return;

    // ================= head (wave 0; verbatim r24 head3b) =================
    {
        const uint4 z = {0u, 0u, 0u, 0u};
        if (lane < 51) {
            *reinterpret_cast<uint4*>(hset + lane * 8) = z;
            *reinterpret_cast<uint4*>(hset + (lane + 51) * 8) = z;
        }
    }
    lgkm0();

    const half8v* __restrict__ e1f8 = (const half8v*)((const char*)ws + 32768);
    const half8v* __restrict__ e2f8 = (const half8v*)((const char*)ws + 45056);

    float biasA[3], bias2A[3], e3w[3];
    #pragma unroll
    for (int nt = 0; nt < 3; ++nt) {
        biasA[nt]  = ws[6000 + nt * 16 + r];
        bias2A[nt] = ws[6048 + nt * 16 + r];
        e3w[nt]    = ws[6096 + nt * 16 + r];
    }

    const uint4* vp4 = (const uint4*)(vloc + r * 36);    // element baseE+r
    const float xl = inp[(size_t)(baseE + r) * 385 + 384];

    f32x4 acc[3] = {{biasA[0], biasA[0], biasA[0], biasA[0]},
                    {biasA[1], biasA[1], biasA[1], biasA[1]},
                    {biasA[2], biasA[2], biasA[2], biasA[2]}};
    #pragma unroll
    for (int ks = 0; ks < 3; ++ks) {
        uint4 aw;
        if (ks < 2) {
            aw = vp4[ks * 4 + g];
        } else {
            if (g == 0)      aw = vp4[8];
            else if (g == 1) { aw.x = pkrtz_u32(xl, 0.0f); aw.y = 0u; aw.z = 0u; aw.w = 0u; }
            else             { aw.x = 0u; aw.y = 0u; aw.z = 0u; aw.w = 0u; }
        }
        const half8v af = __builtin_bit_cast(half8v, aw);
        #pragma unroll
        for (int nt = 0; nt < 3; ++nt)
            acc[nt] = __builtin_amdgcn_mfma_f32_16x16x32_f16(
                af, e1f8[(ks * 3 + nt) * 64 + lane], acc[nt], 0, 0, 0);
    }

    #pragma unroll
    for (int nt = 0; nt < 3; ++nt)
        #pragma unroll
        for (int q = 0; q < 4; ++q)
            hset[(g * 4 + q) * 48 + nt * 16 + r] = (_Float16)crelu(acc[nt][q]);
    lgkm0();

    f32x4 acc2[3] = {{bias2A[0], bias2A[0], bias2A[0], bias2A[0]},
                     {bias2A[1], bias2A[1], bias2A[1], bias2A[1]},
                     {bias2A[2], bias2A[2], bias2A[2], bias2A[2]}};
    #pragma unroll
    for (int ks = 0; ks < 2; ++ks) {
        const half8v af = *reinterpret_cast<const half8v*>(
            &hset[r * 48 + ks * 32 + g * 8]);
        #pragma unroll
        for (int nt = 0; nt < 3; ++nt)
            acc2[nt] = __builtin_amdgcn_mfma_f32_16x16x32_f16(
                af, e2f8[(ks * 3 + nt) * 64 + lane], acc2[nt], 0, 0, 0);
    }

    const float e3b = e3v[0];
    float s[4];
    #pragma unroll
    for (int q = 0; q < 4; ++q) {
        float part = crelu(acc2[0][q]) * e3w[0]
                   + crelu(acc2[1][q]) * e3w[1]
                   + crelu(acc2[2][q]) * e3w[2];
        part += __shfl_xor(part, 1);
        part += __shfl_xor(part, 2);
        part += __shfl_xor(part, 4);
        part += __shfl_xor(part, 8);
        s[q] = crelu(part + e3b);
    }
    if (r == 0) {
        float4 o4 = {s[0], s[1], s[2], s[3]};
        *reinterpret_cast<float4*>(out + baseE + g * 4) = o4;
    }
}

extern "C" void kernel_launch(void* const* d_in, const int* in_sizes, int n_in,
                              void* d_out, int out_size, void* d_ws, size_t ws_size,
                              hipStream_t stream) {
    const float* inp = (const float*)d_in[0];
    const float* W1  = (const float*)d_in[1];
    const float* b1  = (const float*)d_in[2];
    const float* W2  = (const float*)d_in[3];
    const float* b2  = (const float*)d_in[4];
    const float* W3  = (const float*)d_in[5];
    const float* b3  = (const float*)d_in[6];
    const float* E1  = (const float*)d_in[7];
    const float* e1  = (const float*)d_in[8];
    const float* E2  = (const float*)d_in[9];
    const float* e2  = (const float*)d_in[10];
    const float* E3  = (const float*)d_in[11];
    const float* e3  = (const float*)d_in[12];
    float* out = (float*)d_out;
    float* ws  = (float*)d_ws;
    const _Float16* frag = (const _Float16*)((const char*)d_ws + 19200);

    prep_kernel<<<89, 256, 0, stream>>>(W1, W2, W3, E1, E2, e1, e2, E3, ws);

    const int B = 65536;
    lila_kernel<<<B / 16, 256, 0, stream>>>(inp, b1, b2, b3, e3, ws, frag, out);
}

// Round 27
// 39.083 us; speedup vs baseline: 1.1395x; 1.1395x over previous
//
#include <hip/hip_runtime.h>
#include <hip/hip_fp16.h>

typedef _Float16 half8v __attribute__((ext_vector_type(8)));
typedef __fp16  pk16x2 __attribute__((ext_vector_type(2)));
typedef float f32x4 __attribute__((ext_vector_type(4)));

#define DEV __device__ __forceinline__
DEV float crelu(float x) { return fminf(fmaxf(x, -1.0f), 1.0f); }

DEV unsigned int pkrtz_u32(float a, float b) {
    pk16x2 p = __builtin_amdgcn_cvt_pkrtz(a, b);
    return __builtin_bit_cast(unsigned int, p);
}

DEV void lgkm0() { asm volatile("s_waitcnt lgkmcnt(0)" ::: "memory"); }
DEV void cfence() { asm volatile("" ::: "memory"); }

// ---------------------------------------------------------------------------
// ws layout (identical to r19-r24):
//   floats [0, 1152): w3t [16][2] @ 1120 (L3)
//   float 6000: e1bias48 | float 6048: e2bias48 | float 6096: e3p48
//   byte 19200: f16 frags: W1 [3][64][8] (A-side), W2 [64][8] (A-side)
//   byte 32768: e1bf [3 ks][3 nt][64][8] f16  E1^T, K=96
//   byte 45056: e2bf [2 ks][3 nt][64][8] f16  E2^T, K=64
// ---------------------------------------------------------------------------
__global__ void prep_kernel(const float* __restrict__ W1, const float* __restrict__ W2,
                            const float* __restrict__ W3, const float* __restrict__ E1,
                            const float* __restrict__ E2, const float* __restrict__ e1b,
                            const float* __restrict__ e2b, const float* __restrict__ E3,
                            float* __restrict__ ws) {
    int t = threadIdx.x + blockIdx.x * blockDim.x;
    if (t < 864) {
        int s = t >> 4, o = t & 15;
        ws[t] = W1[o * 54 + s];
    } else if (t < 864 + 256) {
        int u = t - 864; int i = u >> 4, o = u & 15;
        ws[t] = W2[o * 16 + i];
    } else if (t < 1120 + 32) {
        int u = t - 1120; int i = u >> 1, o = u & 1;
        ws[t] = W3[o * 16 + i];
    } else if (t >= 8192 && t < 8192 + 1536) {
        _Float16* fr = (_Float16*)((char*)ws + 19200);
        int u = t - 8192;
        int ks = u >> 9, l = (u >> 3) & 63, j = u & 7;
        int n = l & 15;
        int kg = ks * 32 + ((l >> 4) << 3) + j;
        int ox = kg / 24, rem = kg - ox * 24, cy = rem >> 3, f = rem & 7;
        float v = (kg < 72 && f < 6) ? W1[n * 54 + ox * 18 + cy * 6 + f] : 0.0f;
        fr[u] = (_Float16)v;
    } else if (t >= 10240 && t < 10240 + 512) {
        _Float16* fr = (_Float16*)((char*)ws + 19200) + 1536;
        int u = t - 10240;
        int l = u >> 3, j = u & 7;
        int n = l & 15;
        int k = ((l >> 4) << 3) + j;
        float v = (k < 16) ? W2[n * 16 + k] : 0.0f;
        fr[u] = (_Float16)v;
    } else if (t >= 12288 && t < 12288 + 4608) {
        _Float16* fr = (_Float16*)((char*)ws + 32768);
        int u = t - 12288;
        int ks = u / 1536, rem = u % 1536;
        int nt = rem / 512;
        int l = (rem >> 3) & 63, j = u & 7;
        int k = ks * 32 + ((l >> 4) << 3) + j;
        int o = nt * 16 + (l & 15);
        float v = (k < 73 && o < 34) ? E1[o * 73 + k] : 0.0f;
        fr[u] = (_Float16)v;
    } else if (t >= 18432 && t < 18432 + 3072) {
        _Float16* fr = (_Float16*)((char*)ws + 45056);
        int u = t - 18432;
        int ks = u / 1536, rem = u % 1536;
        int nt = rem / 512;
        int l = (rem >> 3) & 63, j = u & 7;
        int k = ks * 32 + ((l >> 4) << 3) + j;
        int o = nt * 16 + (l & 15);
        float v = (k < 34 && o < 34) ? E2[o * 34 + k] : 0.0f;
        fr[u] = (_Float16)v;
    } else if (t >= 22528 && t < 22528 + 48) {
        int u = t - 22528; ws[6000 + u] = (u < 34) ? e1b[u] : 0.0f;
    } else if (t >= 22592 && t < 22592 + 48) {
        int u = t - 22592; ws[6048 + u] = (u < 34) ? e2b[u] : 0.0f;
    } else if (t >= 22656 && t < 22656 + 48) {
        int u = t - 22656; ws[6096 + u] = (u < 34) ? E3[u] : 0.0f;
    }
}

// ---------------------------------------------------------------------------
// FUSED, conv with OPERAND-SWAPPED MFMA (no h LDS at all) — round-24 best:
//  L1: D1[feat][win] = mfma(W1frag /*A*/, gridfrag /*B*/); frag index maps
//      are A/B-symmetric, so tables and grid reads are unchanged.
//  C1 (lane (r,g) holds feats 4g+q of window r) -> crelu -> cvt_pkrtz pairs
//  -> 4 __shfl build the layer-2 B-frag (feats 8g+j of window r); g>=2 = 0.
//  L2: D2[feat][win] = mfma(W2frag, B2) -> h2 in REGISTERS.
//  L3 per tile: per-lane 4-feat dot + 2 shfl_xor g-reduce -> vloc (LDS).
//  Head (wave 0) r19 head3b. LDS: grids 18432 + vloc 2304 + hset 1632.
// ---------------------------------------------------------------------------
__global__ __launch_bounds__(256, 2) void lila_kernel(
    const float* __restrict__ inp,
    const float* __restrict__ b1, const float* __restrict__ b2,
    const float* __restrict__ b3, const float* __restrict__ e3v,
    const float* __restrict__ ws, const _Float16* __restrict__ frag,
    float* __restrict__ out)
{
    __shared__ half8v grids[4 * 288];        // 18432 B
    __shared__ unsigned int vloc[576];       // [4 waves][144] = 2304 B
    __shared__ _Float16 hset[17 * 48];       // 1632 B (head, wave 0)
    const int tid  = threadIdx.x;
    const int wid  = tid >> 6;
    const int lane = tid & 63;
    const int baseE = blockIdx.x * 16;
    const int baseP = baseE + wid * 4;

    half8v* grid = grids + wid * 288;

    const int r = lane & 15;
    const int g = lane >> 4;

    // ---- zero the wave's grid region (288 half8s; pad cells must be 0) ----
    {
        const uint4 z = {0u, 0u, 0u, 0u};
        #pragma unroll
        for (int i = 0; i < 5; ++i) {
            const int idx = lane + i * 64;
            if (i < 4 || idx < 288)
                *reinterpret_cast<uint4*>(grid + idx) = z;
        }
    }
    cfence();

    // ---- stage 4 elements' grids ----
    {
        const int es = lane >> 4, m = lane & 15;
        const float* __restrict__ src = inp + (size_t)(baseP + es) * 385 + 24 * m;
        #pragma unroll
        for (int c = 0; c < 4; ++c) {
            float f0 = src[c * 6 + 0], f1 = src[c * 6 + 1], f2 = src[c * 6 + 2];
            float f3 = src[c * 6 + 3], f4 = src[c * 6 + 4], f5 = src[c * 6 + 5];
            uint4 q;
            q.x = pkrtz_u32(f0, f1);
            q.y = pkrtz_u32(f2, f3);
            q.z = pkrtz_u32(f4, f5);
            q.w = q.z;                        // finite pad (zero-weighted)
            *reinterpret_cast<uint4*>(grid + es * 72 + 4 * m + c) = q;
        }
    }
    cfence();

    {   // ---- conv: 9 tiles, fully register-resident between MFMAs ----
        const half8v* __restrict__ fr8 = (const half8v*)frag;
        half8v W1f0 = fr8[0 * 64 + lane];     // A-side W1, kstep 0..2
        half8v W1f1 = fr8[1 * 64 + lane];
        half8v W1f2 = fr8[2 * 64 + lane];
        half8v W2fA = fr8[3 * 64 + lane];     // A-side W2 (zero for k>=16)

        int off[3];
        #pragma unroll
        for (int ks = 0; ks < 3; ++ks) {
            int c = ks * 4 + g;
            int ox = c / 3, cy = c - 3 * ox;
            off[ks] = ox * 8 + cy;
        }

        // per-lane biases / L3 weights for feats g*4+q
        float b1q[4], b2q[4], w3a[4], w3b[4];
        const float* __restrict__ w3t = ws + 1120;
        #pragma unroll
        for (int q = 0; q < 4; ++q) {
            b1q[q] = b1[g * 4 + q];
            b2q[q] = b2[g * 4 + q];
            w3a[q] = w3t[(g * 4 + q) * 2 + 0];
            w3b[q] = w3t[(g * 4 + q) * 2 + 1];
        }
        const float b30 = b3[0], b31 = b3[1];

        // shfl source lanes for the layer-2 B-frag gather
        const int s0 = r + (((g << 1) + 0) & 3) * 16;
        const int s1 = r + (((g << 1) + 1) & 3) * 16;

        int w = r, ebase = 0;
        #pragma unroll
        for (int t = 0; t < 9; ++t) {
            const int x = (w * 43) >> 8;
            const int y = w - x * 6;
            const int cellb = ebase + x * 8 + y;

            half8v a0 = grid[cellb + off[0]];
            half8v a1 = grid[cellb + off[1]];
            half8v a2 = grid[cellb + off[2]];

            // ---- layer 1 (operand-swapped): D1[feat 4g+q][win r] ----
            f32x4 acc = {b1q[0], b1q[1], b1q[2], b1q[3]};
            acc = __builtin_amdgcn_mfma_f32_16x16x32_f16(W1f0, a0, acc, 0, 0, 0);
            acc = __builtin_amdgcn_mfma_f32_16x16x32_f16(W1f1, a1, acc, 0, 0, 0);
            acc = __builtin_amdgcn_mfma_f32_16x16x32_f16(W1f2, a2, acc, 0, 0, 0);

            // ---- pack h1 pairs, gather layer-2 B-frag via shfl ----
            const unsigned int d0 = pkrtz_u32(crelu(acc[0]), crelu(acc[1]));
            const unsigned int d1 = pkrtz_u32(crelu(acc[2]), crelu(acc[3]));
            uint4 bw;
            bw.x = (unsigned int)__shfl((int)d0, s0);
            bw.y = (unsigned int)__shfl((int)d1, s0);
            bw.z = (unsigned int)__shfl((int)d0, s1);
            bw.w = (unsigned int)__shfl((int)d1, s1);
            if (g >= 2) { bw.x = 0u; bw.y = 0u; bw.z = 0u; bw.w = 0u; }
            const half8v B2in = __builtin_bit_cast(half8v, bw);

            // ---- layer 2: D2[feat 4g+q][win r] ----
            f32x4 c2 = {b2q[0], b2q[1], b2q[2], b2q[3]};
            c2 = __builtin_amdgcn_mfma_f32_16x16x32_f16(W2fA, B2in, c2, 0, 0, 0);

            // ---- layer 3 per tile: 4-feat partial + g-reduce ----
            float v0p = 0.0f, v1p = 0.0f;
            #pragma unroll
            for (int q = 0; q < 4; ++q) {
                const float hv = crelu(c2[q]);
                v0p = fmaf(hv, w3a[q], v0p);
                v1p = fmaf(hv, w3b[q], v1p);
            }
            v0p += __shfl_xor(v0p, 16);
            v0p += __shfl_xor(v0p, 32);
            v1p += __shfl_xor(v1p, 16);
            v1p += __shfl_xor(v1p, 32);
            if (g == 0)
                vloc[wid * 144 + (ebase >> 1) + w] =
                    pkrtz_u32(crelu(v0p + b30), crelu(v1p + b31));

            w += 16;
            if (w >= 36) { w -= 36; ebase += 72; }
        }
    }

    __syncthreads();                          // vloc complete
    if (wid != 0) return;

    // ================= head (wave 0; r19/r22 head3b) =================
    {
        const uint4 z = {0u, 0u, 0u, 0u};
        if (lane < 51) {
            *reinterpret_cast<uint4*>(hset + lane * 8) = z;
            *reinterpret_cast<uint4*>(hset + (lane + 51) * 8) = z;
        }
    }
    lgkm0();

    const half8v* __restrict__ e1f8 = (const half8v*)((const char*)ws + 32768);
    const half8v* __restrict__ e2f8 = (const half8v*)((const char*)ws + 45056);

    float biasA[3], bias2A[3], e3w[3];
    #pragma unroll
    for (int nt = 0; nt < 3; ++nt) {
        biasA[nt]  = ws[6000 + nt * 16 + r];
        bias2A[nt] = ws[6048 + nt * 16 + r];
        e3w[nt]    = ws[6096 + nt * 16 + r];
    }

    const uint4* vp4 = (const uint4*)(vloc + r * 36);    // element baseE+r
    const float xl = inp[(size_t)(baseE + r) * 385 + 384];

    f32x4 acc[3] = {{biasA[0], biasA[0], biasA[0], biasA[0]},
                    {biasA[1], biasA[1], biasA[1], biasA[1]},
                    {biasA[2], biasA[2], biasA[2], biasA[2]}};
    #pragma unroll
    for (int ks = 0; ks < 3; ++ks) {
        uint4 aw;
        if (ks < 2) {
            aw = vp4[ks * 4 + g];
        } else {
            if (g == 0)      aw = vp4[8];
            else if (g == 1) { aw.x = pkrtz_u32(xl, 0.0f); aw.y = 0u; aw.z = 0u; aw.w = 0u; }
            else             { aw.x = 0u; aw.y = 0u; aw.z = 0u; aw.w = 0u; }
        }
        const half8v af = __builtin_bit_cast(half8v, aw);
        #pragma unroll
        for (int nt = 0; nt < 3; ++nt)
            acc[nt] = __builtin_amdgcn_mfma_f32_16x16x32_f16(
                af, e1f8[(ks * 3 + nt) * 64 + lane], acc[nt], 0, 0, 0);
    }

    #pragma unroll
    for (int nt = 0; nt < 3; ++nt)
        #pragma unroll
        for (int q = 0; q < 4; ++q)
            hset[(g * 4 + q) * 48 + nt * 16 + r] = (_Float16)crelu(acc[nt][q]);
    lgkm0();

    f32x4 acc2[3] = {{bias2A[0], bias2A[0], bias2A[0], bias2A[0]},
                     {bias2A[1], bias2A[1], bias2A[1], bias2A[1]},
                     {bias2A[2], bias2A[2], bias2A[2], bias2A[2]}};
    #pragma unroll
    for (int ks = 0; ks < 2; ++ks) {
        const half8v af = *reinterpret_cast<const half8v*>(
            &hset[r * 48 + ks * 32 + g * 8]);
        #pragma unroll
        for (int nt = 0; nt < 3; ++nt)
            acc2[nt] = __builtin_amdgcn_mfma_f32_16x16x32_f16(
                af, e2f8[(ks * 3 + nt) * 64 + lane], acc2[nt], 0, 0, 0);
    }

    const float e3b = e3v[0];
    float s[4];
    #pragma unroll
    for (int q = 0; q < 4; ++q) {
        float part = crelu(acc2[0][q]) * e3w[0]
                   + crelu(acc2[1][q]) * e3w[1]
                   + crelu(acc2[2][q]) * e3w[2];
        part += __shfl_xor(part, 1);
        part += __shfl_xor(part, 2);
        part += __shfl_xor(part, 4);
        part += __shfl_xor(part, 8);
        s[q] = crelu(part + e3b);
    }
    if (r == 0) {
        float4 o4 = {s[0], s[1], s[2], s[3]};
        *reinterpret_cast<float4*>(out + baseE + g * 4) = o4;
    }
}

extern "C" void kernel_launch(void* const* d_in, const int* in_sizes, int n_in,
                              void* d_out, int out_size, void* d_ws, size_t ws_size,
                              hipStream_t stream) {
    const float* inp = (const float*)d_in[0];
    const float* W1  = (const float*)d_in[1];
    const float* b1  = (const float*)d_in[2];
    const float* W2  = (const float*)d_in[3];
    const float* b2  = (const float*)d_in[4];
    const float* W3  = (const float*)d_in[5];
    const float* b3  = (const float*)d_in[6];
    const float* E1  = (const float*)d_in[7];
    const float* e1  = (const float*)d_in[8];
    const float* E2  = (const float*)d_in[9];
    const float* e2  = (const float*)d_in[10];
    const float* E3  = (const float*)d_in[11];
    const float* e3  = (const float*)d_in[12];
    float* out = (float*)d_out;
    float* ws  = (float*)d_ws;
    const _Float16* frag = (const _Float16*)((const char*)d_ws + 19200);

    prep_kernel<<<89, 256, 0, stream>>>(W1, W2, W3, E1, E2, e1, e2, E3, ws);

    const int B = 65536;
    lila_kernel<<<B / 16, 256, 0, stream>>>(inp, b1, b2, b3, e3, ws, frag, out);
}

// Round 28
// 38.979 us; speedup vs baseline: 1.1425x; 1.0027x over previous
//
#include <hip/hip_runtime.h>
#include <hip/hip_fp16.h>

typedef _Float16 half8v __attribute__((ext_vector_type(8)));
typedef __fp16  pk16x2 __attribute__((ext_vector_type(2)));
typedef float f32x4 __attribute__((ext_vector_type(4)));

#define DEV __device__ __forceinline__
DEV float crelu(float x) { return fminf(fmaxf(x, -1.0f), 1.0f); }

DEV unsigned int pkrtz_u32(float a, float b) {
    pk16x2 p = __builtin_amdgcn_cvt_pkrtz(a, b);
    return __builtin_bit_cast(unsigned int, p);
}

DEV void lgkm0() { asm volatile("s_waitcnt lgkmcnt(0)" ::: "memory"); }
DEV void cfence() { asm volatile("" ::: "memory"); }

// ---------------------------------------------------------------------------
// ws layout (identical to r19-r27):
//   floats [0, 1152): w3t [16][2] @ 1120 (L3)
//   float 6000: e1bias48 | float 6048: e2bias48 | float 6096: e3p48
//   byte 19200: f16 frags: W1 [3][64][8] (A-side), W2 [64][8] (A-side)
//   byte 32768: e1bf [3 ks][3 nt][64][8] f16  E1^T, K=96
//   byte 45056: e2bf [2 ks][3 nt][64][8] f16  E2^T, K=64
// ---------------------------------------------------------------------------
__global__ void prep_kernel(const float* __restrict__ W1, const float* __restrict__ W2,
                            const float* __restrict__ W3, const float* __restrict__ E1,
                            const float* __restrict__ E2, const float* __restrict__ e1b,
                            const float* __restrict__ e2b, const float* __restrict__ E3,
                            float* __restrict__ ws) {
    int t = threadIdx.x + blockIdx.x * blockDim.x;
    if (t < 864) {
        int s = t >> 4, o = t & 15;
        ws[t] = W1[o * 54 + s];
    } else if (t < 864 + 256) {
        int u = t - 864; int i = u >> 4, o = u & 15;
        ws[t] = W2[o * 16 + i];
    } else if (t < 1120 + 32) {
        int u = t - 1120; int i = u >> 1, o = u & 1;
        ws[t] = W3[o * 16 + i];
    } else if (t >= 8192 && t < 8192 + 1536) {
        _Float16* fr = (_Float16*)((char*)ws + 19200);
        int u = t - 8192;
        int ks = u >> 9, l = (u >> 3) & 63, j = u & 7;
        int n = l & 15;
        int kg = ks * 32 + ((l >> 4) << 3) + j;
        int ox = kg / 24, rem = kg - ox * 24, cy = rem >> 3, f = rem & 7;
        float v = (kg < 72 && f < 6) ? W1[n * 54 + ox * 18 + cy * 6 + f] : 0.0f;
        fr[u] = (_Float16)v;
    } else if (t >= 10240 && t < 10240 + 512) {
        _Float16* fr = (_Float16*)((char*)ws + 19200) + 1536;
        int u = t - 10240;
        int l = u >> 3, j = u & 7;
        int n = l & 15;
        int k = ((l >> 4) << 3) + j;
        float v = (k < 16) ? W2[n * 16 + k] : 0.0f;
        fr[u] = (_Float16)v;
    } else if (t >= 12288 && t < 12288 + 4608) {
        _Float16* fr = (_Float16*)((char*)ws + 32768);
        int u = t - 12288;
        int ks = u / 1536, rem = u % 1536;
        int nt = rem / 512;
        int l = (rem >> 3) & 63, j = u & 7;
        int k = ks * 32 + ((l >> 4) << 3) + j;
        int o = nt * 16 + (l & 15);
        float v = (k < 73 && o < 34) ? E1[o * 73 + k] : 0.0f;
        fr[u] = (_Float16)v;
    } else if (t >= 18432 && t < 18432 + 3072) {
        _Float16* fr = (_Float16*)((char*)ws + 45056);
        int u = t - 18432;
        int ks = u / 1536, rem = u % 1536;
        int nt = rem / 512;
        int l = (rem >> 3) & 63, j = u & 7;
        int k = ks * 32 + ((l >> 4) << 3) + j;
        int o = nt * 16 + (l & 15);
        float v = (k < 34 && o < 34) ? E2[o * 34 + k] : 0.0f;
        fr[u] = (_Float16)v;
    } else if (t >= 22528 && t < 22528 + 48) {
        int u = t - 22528; ws[6000 + u] = (u < 34) ? e1b[u] : 0.0f;
    } else if (t >= 22592 && t < 22592 + 48) {
        int u = t - 22592; ws[6048 + u] = (u < 34) ? e2b[u] : 0.0f;
    } else if (t >= 22656 && t < 22656 + 48) {
        int u = t - 22656; ws[6096 + u] = (u < 34) ? E3[u] : 0.0f;
    }
}

// ---------------------------------------------------------------------------
// FUSED (r24/r27 structure) + GRID BANK-PADDING (the only change):
//   row stride 8 -> 9 cells (each row shifts 4 banks: 9*16B = 36 dwords ≡ 4)
//   element stride 72 -> 81 cells (each es shifts 4 banks: 81*16B ≡ 4 mod 32)
// Breaks (a) intra-group row aliasing (r, r+6, r+12 same banks) and (b) the
// perfect cross-g-group bank identity of the old 1152B element stride.
// Staging: lane m writes cells (m>>1)*9 + (m&1)*4 + c; pad row 8 (cells
// 72..80, read only by ox=3 chunks at x=5) zeroed by lanes m<9; col-8 cells
// are never read (y+cy <= 7 < 8). Conv reads: cellb = x*9+y, off = ox*9+cy.
// Everything else byte-identical to r24/r27 (39.08 us anchor).
// ---------------------------------------------------------------------------
__global__ __launch_bounds__(256, 2) void lila_kernel(
    const float* __restrict__ inp,
    const float* __restrict__ b1, const float* __restrict__ b2,
    const float* __restrict__ b3, const float* __restrict__ e3v,
    const float* __restrict__ ws, const _Float16* __restrict__ frag,
    float* __restrict__ out)
{
    __shared__ half8v grids[4 * 324];        // 4 waves x 4 els x 81 cells = 20736 B
    __shared__ unsigned int vloc[576];       // [4 waves][144] = 2304 B
    __shared__ _Float16 hset[17 * 48];       // 1632 B (head, wave 0)
    const int tid  = threadIdx.x;
    const int wid  = tid >> 6;
    const int lane = tid & 63;
    const int baseE = blockIdx.x * 16;
    const int baseP = baseE + wid * 4;

    half8v* grid = grids + wid * 324;

    const int r = lane & 15;
    const int g = lane >> 4;

    // ---- stage 4 elements' grids (9-wide rows) + zero pad row 8 ----
    {
        const int es = lane >> 4, m = lane & 15;
        const float* __restrict__ src = inp + (size_t)(baseP + es) * 385 + 24 * m;
        const int wbase = es * 81 + (m >> 1) * 9 + (m & 1) * 4;
        #pragma unroll
        for (int c = 0; c < 4; ++c) {
            float f0 = src[c * 6 + 0], f1 = src[c * 6 + 1], f2 = src[c * 6 + 2];
            float f3 = src[c * 6 + 3], f4 = src[c * 6 + 4], f5 = src[c * 6 + 5];
            uint4 q;
            q.x = pkrtz_u32(f0, f1);
            q.y = pkrtz_u32(f2, f3);
            q.z = pkrtz_u32(f4, f5);
            q.w = q.z;                        // finite pad (zero-weighted)
            *reinterpret_cast<uint4*>(grid + wbase + c) = q;
        }
        if (m < 9) {
            const uint4 z = {0u, 0u, 0u, 0u};
            *reinterpret_cast<uint4*>(grid + es * 81 + 72 + m) = z;
        }
    }
    cfence();

    {   // ---- conv: 9 tiles, fully register-resident between MFMAs ----
        const half8v* __restrict__ fr8 = (const half8v*)frag;
        half8v W1f0 = fr8[0 * 64 + lane];     // A-side W1, kstep 0..2
        half8v W1f1 = fr8[1 * 64 + lane];
        half8v W1f2 = fr8[2 * 64 + lane];
        half8v W2fA = fr8[3 * 64 + lane];     // A-side W2 (zero for k>=16)

        int off[3];
        #pragma unroll
        for (int ks = 0; ks < 3; ++ks) {
            int c = ks * 4 + g;
            int ox = c / 3, cy = c - 3 * ox;
            off[ks] = ox * 9 + cy;            // 9-wide rows
        }

        // per-lane biases / L3 weights for feats g*4+q
        float b1q[4], b2q[4], w3a[4], w3b[4];
        const float* __restrict__ w3t = ws + 1120;
        #pragma unroll
        for (int q = 0; q < 4; ++q) {
            b1q[q] = b1[g * 4 + q];
            b2q[q] = b2[g * 4 + q];
            w3a[q] = w3t[(g * 4 + q) * 2 + 0];
            w3b[q] = w3t[(g * 4 + q) * 2 + 1];
        }
        const float b30 = b3[0], b31 = b3[1];

        // shfl source lanes for the layer-2 B-frag gather
        const int s0 = r + (((g << 1) + 0) & 3) * 16;
        const int s1 = r + (((g << 1) + 1) & 3) * 16;

        int w = r, ebase = 0;                 // ebase counts elements*81 now? no:
        int egrid = 0;                        // element grid base (es*81)
        int evis = 0;                         // element vision base (es*72 halves)
        #pragma unroll
        for (int t = 0; t < 9; ++t) {
            const int x = (w * 43) >> 8;
            const int y = w - x * 6;
            const int cellb = egrid + x * 9 + y;

            half8v a0 = grid[cellb + off[0]];
            half8v a1 = grid[cellb + off[1]];
            half8v a2 = grid[cellb + off[2]];

            // ---- layer 1 (operand-swapped): D1[feat 4g+q][win r] ----
            f32x4 acc = {b1q[0], b1q[1], b1q[2], b1q[3]};
            acc = __builtin_amdgcn_mfma_f32_16x16x32_f16(W1f0, a0, acc, 0, 0, 0);
            acc = __builtin_amdgcn_mfma_f32_16x16x32_f16(W1f1, a1, acc, 0, 0, 0);
            acc = __builtin_amdgcn_mfma_f32_16x16x32_f16(W1f2, a2, acc, 0, 0, 0);

            // ---- pack h1 pairs, gather layer-2 B-frag via shfl ----
            const unsigned int d0 = pkrtz_u32(crelu(acc[0]), crelu(acc[1]));
            const unsigned int d1 = pkrtz_u32(crelu(acc[2]), crelu(acc[3]));
            uint4 bw;
            bw.x = (unsigned int)__shfl((int)d0, s0);
            bw.y = (unsigned int)__shfl((int)d1, s0);
            bw.z = (unsigned int)__shfl((int)d0, s1);
            bw.w = (unsigned int)__shfl((int)d1, s1);
            if (g >= 2) { bw.x = 0u; bw.y = 0u; bw.z = 0u; bw.w = 0u; }
            const half8v B2in = __builtin_bit_cast(half8v, bw);

            // ---- layer 2: D2[feat 4g+q][win r] ----
            f32x4 c2 = {b2q[0], b2q[1], b2q[2], b2q[3]};
            c2 = __builtin_amdgcn_mfma_f32_16x16x32_f16(W2fA, B2in, c2, 0, 0, 0);

            // ---- layer 3 per tile: 4-feat partial + g-reduce ----
            float v0p = 0.0f, v1p = 0.0f;
            #pragma unroll
            for (int q = 0; q < 4; ++q) {
                const float hv = crelu(c2[q]);
                v0p = fmaf(hv, w3a[q], v0p);
                v1p = fmaf(hv, w3b[q], v1p);
            }
            v0p += __shfl_xor(v0p, 16);
            v0p += __shfl_xor(v0p, 32);
            v1p += __shfl_xor(v1p, 16);
            v1p += __shfl_xor(v1p, 32);
            if (g == 0)
                vloc[wid * 144 + (evis >> 1) + w] =
                    pkrtz_u32(crelu(v0p + b30), crelu(v1p + b31));

            w += 16;
            if (w >= 36) { w -= 36; egrid += 81; evis += 72; }
        }
    }

    __syncthreads();                          // vloc complete
    if (wid != 0) return;

    // ================= head (wave 0; r19/r22 head3b) =================
    {
        const uint4 z = {0u, 0u, 0u, 0u};
        if (lane < 51) {
            *reinterpret_cast<uint4*>(hset + lane * 8) = z;
            *reinterpret_cast<uint4*>(hset + (lane + 51) * 8) = z;
        }
    }
    lgkm0();

    const half8v* __restrict__ e1f8 = (const half8v*)((const char*)ws + 32768);
    const half8v* __restrict__ e2f8 = (const half8v*)((const char*)ws + 45056);

    float biasA[3], bias2A[3], e3w[3];
    #pragma unroll
    for (int nt = 0; nt < 3; ++nt) {
        biasA[nt]  = ws[6000 + nt * 16 + r];
        bias2A[nt] = ws[6048 + nt * 16 + r];
        e3w[nt]    = ws[6096 + nt * 16 + r];
    }

    const uint4* vp4 = (const uint4*)(vloc + r * 36);    // element baseE+r
    const float xl = inp[(size_t)(baseE + r) * 385 + 384];

    f32x4 acc[3] = {{biasA[0], biasA[0], biasA[0], biasA[0]},
                    {biasA[1], biasA[1], biasA[1], biasA[1]},
                    {biasA[2], biasA[2], biasA[2], biasA[2]}};
    #pragma unroll
    for (int ks = 0; ks < 3; ++ks) {
        uint4 aw;
        if (ks < 2) {
            aw = vp4[ks * 4 + g];
        } else {
            if (g == 0)      aw = vp4[8];
            else if (g == 1) { aw.x = pkrtz_u32(xl, 0.0f); aw.y = 0u; aw.z = 0u; aw.w = 0u; }
            else             { aw.x = 0u; aw.y = 0u; aw.z = 0u; aw.w = 0u; }
        }
        const half8v af = __builtin_bit_cast(half8v, aw);
        #pragma unroll
        for (int nt = 0; nt < 3; ++nt)
            acc[nt] = __builtin_amdgcn_mfma_f32_16x16x32_f16(
                af, e1f8[(ks * 3 + nt) * 64 + lane], acc[nt], 0, 0, 0);
    }

    #pragma unroll
    for (int nt = 0; nt < 3; ++nt)
        #pragma unroll
        for (int q = 0; q < 4; ++q)
            hset[(g * 4 + q) * 48 + nt * 16 + r] = (_Float16)crelu(acc[nt][q]);
    lgkm0();

    f32x4 acc2[3] = {{bias2A[0], bias2A[0], bias2A[0], bias2A[0]},
                     {bias2A[1], bias2A[1], bias2A[1], bias2A[1]},
                     {bias2A[2], bias2A[2], bias2A[2], bias2A[2]}};
    #pragma unroll
    for (int ks = 0; ks < 2; ++ks) {
        const half8v af = *reinterpret_cast<const half8v*>(
            &hset[r * 48 + ks * 32 + g * 8]);
        #pragma unroll
        for (int nt = 0; nt < 3; ++nt)
            acc2[nt] = __builtin_amdgcn_mfma_f32_16x16x32_f16(
                af, e2f8[(ks * 3 + nt) * 64 + lane], acc2[nt], 0, 0, 0);
    }

    const float e3b = e3v[0];
    float s[4];
    #pragma unroll
    for (int q = 0; q < 4; ++q) {
        float part = crelu(acc2[0][q]) * e3w[0]
                   + crelu(acc2[1][q]) * e3w[1]
                   + crelu(acc2[2][q]) * e3w[2];
        part += __shfl_xor(part, 1);
        part += __shfl_xor(part, 2);
        part += __shfl_xor(part, 4);
        part += __shfl_xor(part, 8);
        s[q] = crelu(part + e3b);
    }
    if (r == 0) {
        float4 o4 = {s[0], s[1], s[2], s[3]};
        *reinterpret_cast<float4*>(out + baseE + g * 4) = o4;
    }
}

extern "C" void kernel_launch(void* const* d_in, const int* in_sizes, int n_in,
                              void* d_out, int out_size, void* d_ws, size_t ws_size,
                              hipStream_t stream) {
    const float* inp = (const float*)d_in[0];
    const float* W1  = (const float*)d_in[1];
    const float* b1  = (const float*)d_in[2];
    const float* W2  = (const float*)d_in[3];
    const float* b2  = (const float*)d_in[4];
    const float* W3  = (const float*)d_in[5];
    const float* b3  = (const float*)d_in[6];
    const float* E1  = (const float*)d_in[7];
    const float* e1  = (const float*)d_in[8];
    const float* E2  = (const float*)d_in[9];
    const float* e2  = (const float*)d_in[10];
    const float* E3  = (const float*)d_in[11];
    const float* e3  = (const float*)d_in[12];
    float* out = (float*)d_out;
    float* ws  = (float*)d_ws;
    const _Float16* frag = (const _Float16*)((const char*)d_ws + 19200);

    prep_kernel<<<89, 256, 0, stream>>>(W1, W2, W3, E1, E2, e1, e2, E3, ws);

    const int B = 65536;
    lila_kernel<<<B / 16, 256, 0, stream>>>(inp, b1, b2, b3, e3, ws, frag, out);
}

// Round 29
// 38.794 us; speedup vs baseline: 1.1479x; 1.0048x over previous
//
#include <hip/hip_runtime.h>
#include <hip/hip_fp16.h>

typedef _Float16 half8v __attribute__((ext_vector_type(8)));
typedef __fp16  pk16x2 __attribute__((ext_vector_type(2)));
typedef float f32x4 __attribute__((ext_vector_type(4)));

#define DEV __device__ __forceinline__
DEV float crelu(float x) { return fminf(fmaxf(x, -1.0f), 1.0f); }

DEV unsigned int pkrtz_u32(float a, float b) {
    pk16x2 p = __builtin_amdgcn_cvt_pkrtz(a, b);
    return __builtin_bit_cast(unsigned int, p);
}

DEV void lgkm0() { asm volatile("s_waitcnt lgkmcnt(0)" ::: "memory"); }
DEV void cfence() { asm volatile("" ::: "memory"); }

// ---------------------------------------------------------------------------
// ws layout (identical to r19-r28):
//   floats [0, 1152): w3t [16][2] @ 1120 (L3)
//   float 6000: e1bias48 | float 6048: e2bias48 | float 6096: e3p48
//   byte 19200: f16 frags: W1 [3][64][8] (A-side), W2 [64][8] (A-side)
//   byte 32768: e1bf [3 ks][3 nt][64][8] f16  E1^T, K=96
//   byte 45056: e2bf [2 ks][3 nt][64][8] f16  E2^T, K=64
// ---------------------------------------------------------------------------
__global__ void prep_kernel(const float* __restrict__ W1, const float* __restrict__ W2,
                            const float* __restrict__ W3, const float* __restrict__ E1,
                            const float* __restrict__ E2, const float* __restrict__ e1b,
                            const float* __restrict__ e2b, const float* __restrict__ E3,
                            float* __restrict__ ws) {
    int t = threadIdx.x + blockIdx.x * blockDim.x;
    if (t < 864) {
        int s = t >> 4, o = t & 15;
        ws[t] = W1[o * 54 + s];
    } else if (t < 864 + 256) {
        int u = t - 864; int i = u >> 4, o = u & 15;
        ws[t] = W2[o * 16 + i];
    } else if (t < 1120 + 32) {
        int u = t - 1120; int i = u >> 1, o = u & 1;
        ws[t] = W3[o * 16 + i];
    } else if (t >= 8192 && t < 8192 + 1536) {
        _Float16* fr = (_Float16*)((char*)ws + 19200);
        int u = t - 8192;
        int ks = u >> 9, l = (u >> 3) & 63, j = u & 7;
        int n = l & 15;
        int kg = ks * 32 + ((l >> 4) << 3) + j;
        int ox = kg / 24, rem = kg - ox * 24, cy = rem >> 3, f = rem & 7;
        float v = (kg < 72 && f < 6) ? W1[n * 54 + ox * 18 + cy * 6 + f] : 0.0f;
        fr[u] = (_Float16)v;
    } else if (t >= 10240 && t < 10240 + 512) {
        _Float16* fr = (_Float16*)((char*)ws + 19200) + 1536;
        int u = t - 10240;
        int l = u >> 3, j = u & 7;
        int n = l & 15;
        int k = ((l >> 4) << 3) + j;
        float v = (k < 16) ? W2[n * 16 + k] : 0.0f;
        fr[u] = (_Float16)v;
    } else if (t >= 12288 && t < 12288 + 4608) {
        _Float16* fr = (_Float16*)((char*)ws + 32768);
        int u = t - 12288;
        int ks = u / 1536, rem = u % 1536;
        int nt = rem / 512;
        int l = (rem >> 3) & 63, j = u & 7;
        int k = ks * 32 + ((l >> 4) << 3) + j;
        int o = nt * 16 + (l & 15);
        float v = (k < 73 && o < 34) ? E1[o * 73 + k] : 0.0f;
        fr[u] = (_Float16)v;
    } else if (t >= 18432 && t < 18432 + 3072) {
        _Float16* fr = (_Float16*)((char*)ws + 45056);
        int u = t - 18432;
        int ks = u / 1536, rem = u % 1536;
        int nt = rem / 512;
        int l = (rem >> 3) & 63, j = u & 7;
        int k = ks * 32 + ((l >> 4) << 3) + j;
        int o = nt * 16 + (l & 15);
        float v = (k < 34 && o < 34) ? E2[o * 34 + k] : 0.0f;
        fr[u] = (_Float16)v;
    } else if (t >= 22528 && t < 22528 + 48) {
        int u = t - 22528; ws[6000 + u] = (u < 34) ? e1b[u] : 0.0f;
    } else if (t >= 22592 && t < 22592 + 48) {
        int u = t - 22592; ws[6048 + u] = (u < 34) ? e2b[u] : 0.0f;
    } else if (t >= 22656 && t < 22656 + 48) {
        int u = t - 22656; ws[6096 + u] = (u < 34) ? E3[u] : 0.0f;
    }
}

// ---------------------------------------------------------------------------
// FUSED (r28 structure: operand-swapped conv, bank-padded grid 9/81 strides)
// + VECTORIZED STAGING (the only change): each lane's 24 contiguous input
// floats loaded via __builtin_memcpy (4B-aligned) so the backend can emit
// 6 global_load_dwordx4 instead of 24 scalar dwords.
// ---------------------------------------------------------------------------
__global__ __launch_bounds__(256, 2) void lila_kernel(
    const float* __restrict__ inp,
    const float* __restrict__ b1, const float* __restrict__ b2,
    const float* __restrict__ b3, const float* __restrict__ e3v,
    const float* __restrict__ ws, const _Float16* __restrict__ frag,
    float* __restrict__ out)
{
    __shared__ half8v grids[4 * 324];        // 4 waves x 4 els x 81 cells
    __shared__ unsigned int vloc[576];       // [4 waves][144]
    __shared__ _Float16 hset[17 * 48];       // head (wave 0)
    const int tid  = threadIdx.x;
    const int wid  = tid >> 6;
    const int lane = tid & 63;
    const int baseE = blockIdx.x * 16;
    const int baseP = baseE + wid * 4;

    half8v* grid = grids + wid * 324;

    const int r = lane & 15;
    const int g = lane >> 4;

    // ---- stage 4 elements' grids (9-wide rows) + zero pad row 8 ----
    {
        const int es = lane >> 4, m = lane & 15;
        const float* __restrict__ src = inp + (size_t)(baseP + es) * 385 + 24 * m;
        float vv[24];
        #pragma unroll
        for (int c4 = 0; c4 < 6; ++c4) {
            float4 tq;
            __builtin_memcpy(&tq, src + c4 * 4, 16);   // 4B-aligned dwordx4
            vv[c4 * 4 + 0] = tq.x; vv[c4 * 4 + 1] = tq.y;
            vv[c4 * 4 + 2] = tq.z; vv[c4 * 4 + 3] = tq.w;
        }
        const int wbase = es * 81 + (m >> 1) * 9 + (m & 1) * 4;
        #pragma unroll
        for (int c = 0; c < 4; ++c) {
            uint4 q;
            q.x = pkrtz_u32(vv[c * 6 + 0], vv[c * 6 + 1]);
            q.y = pkrtz_u32(vv[c * 6 + 2], vv[c * 6 + 3]);
            q.z = pkrtz_u32(vv[c * 6 + 4], vv[c * 6 + 5]);
            q.w = q.z;                        // finite pad (zero-weighted)
            *reinterpret_cast<uint4*>(grid + wbase + c) = q;
        }
        if (m < 9) {
            const uint4 z = {0u, 0u, 0u, 0u};
            *reinterpret_cast<uint4*>(grid + es * 81 + 72 + m) = z;
        }
    }
    cfence();

    {   // ---- conv: 9 tiles, fully register-resident between MFMAs ----
        const half8v* __restrict__ fr8 = (const half8v*)frag;
        half8v W1f0 = fr8[0 * 64 + lane];
        half8v W1f1 = fr8[1 * 64 + lane];
        half8v W1f2 = fr8[2 * 64 + lane];
        half8v W2fA = fr8[3 * 64 + lane];

        int off[3];
        #pragma unroll
        for (int ks = 0; ks < 3; ++ks) {
            int c = ks * 4 + g;
            int ox = c / 3, cy = c - 3 * ox;
            off[ks] = ox * 9 + cy;            // 9-wide rows
        }

        float b1q[4], b2q[4], w3a[4], w3b[4];
        const float* __restrict__ w3t = ws + 1120;
        #pragma unroll
        for (int q = 0; q < 4; ++q) {
            b1q[q] = b1[g * 4 + q];
            b2q[q] = b2[g * 4 + q];
            w3a[q] = w3t[(g * 4 + q) * 2 + 0];
            w3b[q] = w3t[(g * 4 + q) * 2 + 1];
        }
        const float b30 = b3[0], b31 = b3[1];

        const int s0 = r + (((g << 1) + 0) & 3) * 16;
        const int s1 = r + (((g << 1) + 1) & 3) * 16;

        int w = r;
        int egrid = 0;                        // element grid base (es*81)
        int evis = 0;                         // element vision base (es*72 halves)
        #pragma unroll
        for (int t = 0; t < 9; ++t) {
            const int x = (w * 43) >> 8;
            const int y = w - x * 6;
            const int cellb = egrid + x * 9 + y;

            half8v a0 = grid[cellb + off[0]];
            half8v a1 = grid[cellb + off[1]];
            half8v a2 = grid[cellb + off[2]];

            f32x4 acc = {b1q[0], b1q[1], b1q[2], b1q[3]};
            acc = __builtin_amdgcn_mfma_f32_16x16x32_f16(W1f0, a0, acc, 0, 0, 0);
            acc = __builtin_amdgcn_mfma_f32_16x16x32_f16(W1f1, a1, acc, 0, 0, 0);
            acc = __builtin_amdgcn_mfma_f32_16x16x32_f16(W1f2, a2, acc, 0, 0, 0);

            const unsigned int d0 = pkrtz_u32(crelu(acc[0]), crelu(acc[1]));
            const unsigned int d1 = pkrtz_u32(crelu(acc[2]), crelu(acc[3]));
            uint4 bw;
            bw.x = (unsigned int)__shfl((int)d0, s0);
            bw.y = (unsigned int)__shfl((int)d1, s0);
            bw.z = (unsigned int)__shfl((int)d0, s1);
            bw.w = (unsigned int)__shfl((int)d1, s1);
            if (g >= 2) { bw.x = 0u; bw.y = 0u; bw.z = 0u; bw.w = 0u; }
            const half8v B2in = __builtin_bit_cast(half8v, bw);

            f32x4 c2 = {b2q[0], b2q[1], b2q[2], b2q[3]};
            c2 = __builtin_amdgcn_mfma_f32_16x16x32_f16(W2fA, B2in, c2, 0, 0, 0);

            float v0p = 0.0f, v1p = 0.0f;
            #pragma unroll
            for (int q = 0; q < 4; ++q) {
                const float hv = crelu(c2[q]);
                v0p = fmaf(hv, w3a[q], v0p);
                v1p = fmaf(hv, w3b[q], v1p);
            }
            v0p += __shfl_xor(v0p, 16);
            v0p += __shfl_xor(v0p, 32);
            v1p += __shfl_xor(v1p, 16);
            v1p += __shfl_xor(v1p, 32);
            if (g == 0)
                vloc[wid * 144 + (evis >> 1) + w] =
                    pkrtz_u32(crelu(v0p + b30), crelu(v1p + b31));

            w += 16;
            if (w >= 36) { w -= 36; egrid += 81; evis += 72; }
        }
    }

    __syncthreads();                          // vloc complete
    if (wid != 0) return;

    // ================= head (wave 0; r19/r22 head3b) =================
    {
        const uint4 z = {0u, 0u, 0u, 0u};
        if (lane < 51) {
            *reinterpret_cast<uint4*>(hset + lane * 8) = z;
            *reinterpret_cast<uint4*>(hset + (lane + 51) * 8) = z;
        }
    }
    lgkm0();

    const half8v* __restrict__ e1f8 = (const half8v*)((const char*)ws + 32768);
    const half8v* __restrict__ e2f8 = (const half8v*)((const char*)ws + 45056);

    float biasA[3], bias2A[3], e3w[3];
    #pragma unroll
    for (int nt = 0; nt < 3; ++nt) {
        biasA[nt]  = ws[6000 + nt * 16 + r];
        bias2A[nt] = ws[6048 + nt * 16 + r];
        e3w[nt]    = ws[6096 + nt * 16 + r];
    }

    const uint4* vp4 = (const uint4*)(vloc + r * 36);    // element baseE+r
    const float xl = inp[(size_t)(baseE + r) * 385 + 384];

    f32x4 acc[3] = {{biasA[0], biasA[0], biasA[0], biasA[0]},
                    {biasA[1], biasA[1], biasA[1], biasA[1]},
                    {biasA[2], biasA[2], biasA[2], biasA[2]}};
    #pragma unroll
    for (int ks = 0; ks < 3; ++ks) {
        uint4 aw;
        if (ks < 2) {
            aw = vp4[ks * 4 + g];
        } else {
            if (g == 0)      aw = vp4[8];
            else if (g == 1) { aw.x = pkrtz_u32(xl, 0.0f); aw.y = 0u; aw.z = 0u; aw.w = 0u; }
            else             { aw.x = 0u; aw.y = 0u; aw.z = 0u; aw.w = 0u; }
        }
        const half8v af = __builtin_bit_cast(half8v, aw);
        #pragma unroll
        for (int nt = 0; nt < 3; ++nt)
            acc[nt] = __builtin_amdgcn_mfma_f32_16x16x32_f16(
                af, e1f8[(ks * 3 + nt) * 64 + lane], acc[nt], 0, 0, 0);
    }

    #pragma unroll
    for (int nt = 0; nt < 3; ++nt)
        #pragma unroll
        for (int q = 0; q < 4; ++q)
            hset[(g * 4 + q) * 48 + nt * 16 + r] = (_Float16)crelu(acc[nt][q]);
    lgkm0();

    f32x4 acc2[3] = {{bias2A[0], bias2A[0], bias2A[0], bias2A[0]},
                     {bias2A[1], bias2A[1], bias2A[1], bias2A[1]},
                     {bias2A[2], bias2A[2], bias2A[2], bias2A[2]}};
    #pragma unroll
    for (int ks = 0; ks < 2; ++ks) {
        const half8v af = *reinterpret_cast<const half8v*>(
            &hset[r * 48 + ks * 32 + g * 8]);
        #pragma unroll
        for (int nt = 0; nt < 3; ++nt)
            acc2[nt] = __builtin_amdgcn_mfma_f32_16x16x32_f16(
                af, e2f8[(ks * 3 + nt) * 64 + lane], acc2[nt], 0, 0, 0);
    }

    const float e3b = e3v[0];
    float s[4];
    #pragma unroll
    for (int q = 0; q < 4; ++q) {
        float part = crelu(acc2[0][q]) * e3w[0]
                   + crelu(acc2[1][q]) * e3w[1]
                   + crelu(acc2[2][q]) * e3w[2];
        part += __shfl_xor(part, 1);
        part += __shfl_xor(part, 2);
        part += __shfl_xor(part, 4);
        part += __shfl_xor(part, 8);
        s[q] = crelu(part + e3b);
    }
    if (r == 0) {
        float4 o4 = {s[0], s[1], s[2], s[3]};
        *reinterpret_cast<float4*>(out + baseE + g * 4) = o4;
    }
}

extern "C" void kernel_launch(void* const* d_in, const int* in_sizes, int n_in,
                              void* d_out, int out_size, void* d_ws, size_t ws_size,
                              hipStream_t stream) {
    const float* inp = (const float*)d_in[0];
    const float* W1  = (const float*)d_in[1];
    const float* b1  = (const float*)d_in[2];
    const float* W2  = (const float*)d_in[3];
    const float* b2  = (const float*)d_in[4];
    const float* W3  = (const float*)d_in[5];
    const float* b3  = (const float*)d_in[6];
    const float* E1  = (const float*)d_in[7];
    const float* e1  = (const float*)d_in[8];
    const float* E2  = (const float*)d_in[9];
    const float* e2  = (const float*)d_in[10];
    const float* E3  = (const float*)d_in[11];
    const float* e3  = (const float*)d_in[12];
    float* out = (float*)d_out;
    float* ws  = (float*)d_ws;
    const _Float16* frag = (const _Float16*)((const char*)d_ws + 19200);

    prep_kernel<<<89, 256, 0, stream>>>(W1, W2, W3, E1, E2, e1, e2, E3, ws);

    const int B = 65536;
    lila_kernel<<<B / 16, 256, 0, stream>>>(inp, b1, b2, b3, e3, ws, frag, out);
}